// Round 1
// baseline (588.839 us; speedup 1.0000x reference)
//
#include <hip/hip_runtime.h>
#include <hip/hip_bf16.h>

#define N_TOK 8192
#define DDIM 1024
#define HDIM 4096
#define NEXP 8
#define TOPK 2
#define NK (N_TOK*TOPK)
#define BM 128
#define BN 128
#define BK 64
#define MAXT 136   // max padded M-tiles: 16384/128 + 8 pad tiles

typedef __hip_bfloat16 bf16;
typedef __attribute__((ext_vector_type(8))) short bf16x8;
typedef __attribute__((ext_vector_type(4))) float f32x4;

__device__ __forceinline__ void gload16(const void* g, void* lds) {
  auto l = (__attribute__((address_space(3))) unsigned int*)(unsigned int)(unsigned long long)lds;
  auto gg = (const __attribute__((address_space(1))) unsigned int*)(unsigned long long)g;
  __builtin_amdgcn_global_load_lds(gg, l, 16, 0, 0);
}

// ---- router ----
__global__ void k_detect(const int* __restrict__ idx, int* __restrict__ flag) {
  if (threadIdx.x == 0 && blockIdx.x == 0) {
    int allz = 1;
    for (int i = 1; i < 32; i += 2) allz &= (idx[i] == 0);
    *flag = allz ? 2 : 1;   // 2 => int64 little-endian, 1 => int32
  }
}

__global__ void k_count(const int* __restrict__ idx, const int* __restrict__ flag,
                        int* __restrict__ cnt) {
  int r = blockIdx.x * blockDim.x + threadIdx.x;
  if (r >= NK) return;
  int s = *flag;
  int e = idx[r * s];
  e = min(max(e, 0), NEXP - 1);
  atomicAdd(&cnt[e], 1);
}

__global__ void k_scan(const int* __restrict__ cnt, int* __restrict__ offp,
                       int* __restrict__ off2, int* __restrict__ texp,
                       int* __restrict__ tok) {
  __shared__ int so[NEXP + 1], sc[NEXP];
  int tid = threadIdx.x;
  if (tid == 0) {
    int cum = 0;
    for (int e = 0; e < NEXP; e++) {
      so[e] = cum; sc[e] = cnt[e];
      cum += ((cnt[e] + BM - 1) / BM) * BM;
    }
    so[NEXP] = cum;
    for (int e = 0; e <= NEXP; e++) offp[e] = so[e];
  }
  __syncthreads();
  if (tid < NEXP) off2[tid] = so[tid];
  int total_tiles = so[NEXP] / BM;
  for (int t = tid; t < MAXT; t += blockDim.x) {
    int e = -1;
    if (t < total_tiles) {
      for (int q = 0; q < NEXP; q++)
        if (t * BM >= so[q] && t * BM < so[q + 1]) e = q;
    }
    texp[t] = e;
  }
  for (int e = 0; e < NEXP; e++) {
    int start = so[e] + sc[e], end = so[e + 1];
    for (int i = start + tid; i < end; i += blockDim.x) tok[i] = 0;
  }
}

__global__ void k_scatter(const int* __restrict__ idx, const int* __restrict__ flag,
                          int* __restrict__ off2, int* __restrict__ tok,
                          int* __restrict__ pos) {
  int r = blockIdx.x * blockDim.x + threadIdx.x;
  if (r >= NK) return;
  int s = *flag;
  int e = idx[r * s];
  e = min(max(e, 0), NEXP - 1);
  int p = atomicAdd(&off2[e], 1);
  tok[p] = r >> 1;
  pos[r] = p;
}

// ---- converts ----
__global__ void k_cvt_x(const float* __restrict__ x, bf16* __restrict__ xb) {
  int i = blockIdx.x * blockDim.x + threadIdx.x;   // over N*D/8
  if (i >= N_TOK * DDIM / 8) return;
  float4 a = ((const float4*)x)[(size_t)i * 2];
  float4 b = ((const float4*)x)[(size_t)i * 2 + 1];
  union { bf16 h[8]; uint4 v; } u;
  u.h[0] = __float2bfloat16(a.x); u.h[1] = __float2bfloat16(a.y);
  u.h[2] = __float2bfloat16(a.z); u.h[3] = __float2bfloat16(a.w);
  u.h[4] = __float2bfloat16(b.x); u.h[5] = __float2bfloat16(b.y);
  u.h[6] = __float2bfloat16(b.z); u.h[7] = __float2bfloat16(b.w);
  *(uint4*)&xb[(size_t)i * 8] = u.v;
}

// [E][R][C] fp32 -> [E][C][R] bf16
__global__ void k_transpose(const float* __restrict__ in, bf16* __restrict__ out,
                            int R, int C) {
  __shared__ float t[32][33];
  size_t ebase = (size_t)blockIdx.z * R * C;
  int tx = threadIdx.x & 31, ty = threadIdx.x >> 5;
  int c0 = blockIdx.x * 32, r0 = blockIdx.y * 32;
#pragma unroll
  for (int j = 0; j < 4; j++)
    t[ty + j * 8][tx] = in[ebase + (size_t)(r0 + ty + j * 8) * C + c0 + tx];
  __syncthreads();
#pragma unroll
  for (int j = 0; j < 4; j++)
    out[ebase + (size_t)(c0 + ty + j * 8) * R + r0 + tx] =
        __float2bfloat16(t[tx][ty + j * 8]);
}

// ---- grouped GEMM ----
// MODE 0: A gathered by tok ids (Xb), +bias ReLU, bf16 out (slice-local rows)
// MODE 1: A = h (slice-local rows), +bias, f32 out (global rows)
template<int MODE>
__global__ __launch_bounds__(256, 2) void k_gemm(
    const bf16* __restrict__ A, const bf16* __restrict__ Bt,
    const float* __restrict__ bias, const int* __restrict__ texp,
    const int* __restrict__ tok, int K, int Ncols, int tile_base,
    void* __restrict__ Cout)
{
  int tm = tile_base + blockIdx.y;
  int e = texp[tm];
  if (e < 0) return;
  int tn = blockIdx.x;
  int tid = threadIdx.x, lane = tid & 63, wid = tid >> 6;
  int wm = wid >> 1, wn = wid & 1;

  __shared__ __align__(16) bf16 As[BM * BK];
  __shared__ __align__(16) bf16 Bs[BN * BK];

  const bf16* Bexp = Bt + ((size_t)e * Ncols + (size_t)tn * BN) * K;

  f32x4 acc[4][4];
#pragma unroll
  for (int i = 0; i < 4; i++)
#pragma unroll
    for (int j = 0; j < 4; j++) acc[i][j] = (f32x4){0.f, 0.f, 0.f, 0.f};

  for (int k0 = 0; k0 < K; k0 += BK) {
#pragma unroll
    for (int it = 0; it < 4; ++it) {
      int ch = it * 256 + tid;
      int i = ch >> 3, c = ch & 7;
      int cs = c ^ (i & 7);                  // source-side swizzle (rule #21)
      const bf16* src;
      if (MODE == 0) {
        int row = tok[tm * BM + i];
        src = A + (size_t)row * K + k0 + cs * 8;
      } else {
        int row = (tm - tile_base) * BM + i;
        src = A + (size_t)row * K + k0 + cs * 8;
      }
      gload16(src, (char*)As + (it * 256 + wid * 64) * 16);
    }
#pragma unroll
    for (int it = 0; it < 4; ++it) {
      int ch = it * 256 + tid;
      int i = ch >> 3, c = ch & 7;
      int cs = c ^ (i & 7);
      const bf16* src = Bexp + (size_t)i * K + k0 + cs * 8;
      gload16(src, (char*)Bs + (it * 256 + wid * 64) * 16);
    }
    asm volatile("s_waitcnt vmcnt(0)" ::: "memory");
    __syncthreads();

#pragma unroll
    for (int kh = 0; kh < 2; ++kh) {
      bf16x8 av[4], bv[4];
      int lr = lane & 15, kg = lane >> 4;
#pragma unroll
      for (int mi = 0; mi < 4; mi++) {
        int m = wm * 64 + mi * 16 + lr;
        int ph = (kh * 4 + kg) ^ (m & 7);    // swizzled read
        av[mi] = *(const bf16x8*)&As[m * BK + ph * 8];
      }
#pragma unroll
      for (int ni = 0; ni < 4; ni++) {
        int n = wn * 64 + ni * 16 + lr;
        int ph = (kh * 4 + kg) ^ (n & 7);
        bv[ni] = *(const bf16x8*)&Bs[n * BK + ph * 8];
      }
#pragma unroll
      for (int mi = 0; mi < 4; mi++)
#pragma unroll
        for (int ni = 0; ni < 4; ni++)
          acc[mi][ni] = __builtin_amdgcn_mfma_f32_16x16x32_bf16(
              av[mi], bv[ni], acc[mi][ni], 0, 0, 0);
    }
    __syncthreads();
  }

  const float* be = bias + (size_t)e * Ncols;
  int lr = lane & 15, rg = lane >> 4;
#pragma unroll
  for (int ni = 0; ni < 4; ++ni) {
    int n = tn * BN + wn * 64 + ni * 16 + lr;
    float bv = be[n];
#pragma unroll
    for (int mi = 0; mi < 4; ++mi) {
#pragma unroll
      for (int j = 0; j < 4; j++) {
        int mrow = wm * 64 + mi * 16 + rg * 4 + j;   // row within tile (C/D map m89)
        float v = acc[mi][ni][j] + bv;
        if (MODE == 0) {
          v = fmaxf(v, 0.f);
          ((bf16*)Cout)[(size_t)((tm - tile_base) * BM + mrow) * Ncols + n] =
              __float2bfloat16(v);
        } else {
          ((float*)Cout)[(size_t)(tm * BM + mrow) * Ncols + n] = v;
        }
      }
    }
  }
}

// ---- combine ----
__global__ void k_combine(const float* __restrict__ y, const float* __restrict__ prob,
                          const int* __restrict__ pos, float* __restrict__ out) {
  int gid = blockIdx.x * blockDim.x + threadIdx.x;  // over N*D/4
  if (gid >= N_TOK * DDIM / 4) return;
  int n = gid / (DDIM / 4);
  int d4 = gid % (DDIM / 4);
  int r0 = pos[2 * n], r1 = pos[2 * n + 1];
  float p0 = prob[2 * n], p1 = prob[2 * n + 1];
  float4 a = *(const float4*)&y[(size_t)r0 * DDIM + (size_t)d4 * 4];
  float4 b = *(const float4*)&y[(size_t)r1 * DDIM + (size_t)d4 * 4];
  float4 o;
  o.x = p0 * a.x + p1 * b.x; o.y = p0 * a.y + p1 * b.y;
  o.z = p0 * a.z + p1 * b.z; o.w = p0 * a.w + p1 * b.w;
  *(float4*)&out[(size_t)n * DDIM + (size_t)d4 * 4] = o;
  if (gid == 0) out[(size_t)N_TOK * DDIM] = 0.f;   // total_loss
}

extern "C" void kernel_launch(void* const* d_in, const int* in_sizes, int n_in,
                              void* d_out, int out_size, void* d_ws, size_t ws_size,
                              hipStream_t stream) {
  const float* x    = (const float*)d_in[0];
  const float* prob = (const float*)d_in[1];
  const int*   idx  = (const int*)d_in[2];
  const float* W1   = (const float*)d_in[3];
  const float* b1   = (const float*)d_in[4];
  const float* W2   = (const float*)d_in[5];
  const float* b2   = (const float*)d_in[6];
  float* out = (float*)d_out;

  char* ws = (char*)d_ws;
  size_t cur = 0;
  auto alloc = [&](size_t bytes) -> void* {
    cur = (cur + 255) & ~(size_t)255;
    void* p = ws + cur; cur += bytes; return p;
  };
  int* cnt   = (int*)alloc(NEXP * 4);
  int* offp  = (int*)alloc((NEXP + 1) * 4);
  int* off2  = (int*)alloc(NEXP * 4);
  int* flag  = (int*)alloc(4);
  int* texp  = (int*)alloc(MAXT * 4);
  int* tok   = (int*)alloc((size_t)MAXT * BM * 4);
  int* pos   = (int*)alloc((size_t)NK * 4);
  bf16* Xb   = (bf16*)alloc((size_t)N_TOK * DDIM * 2);
  bf16* W1t  = (bf16*)alloc((size_t)NEXP * HDIM * DDIM * 2);
  bf16* W2t  = (bf16*)alloc((size_t)NEXP * DDIM * HDIM * 2);
  float* ybuf = (float*)alloc((size_t)MAXT * BM * DDIM * 4);
  cur = (cur + 255) & ~(size_t)255;
  size_t h_off = cur;
  size_t h_avail = ws_size > h_off ? ws_size - h_off : 0;
  long long ts_ll = (long long)(h_avail / ((size_t)BM * HDIM * 2));
  int ts = (int)(ts_ll < 1 ? 1 : (ts_ll > MAXT ? MAXT : ts_ll));
  bf16* hbuf = (bf16*)(ws + h_off);

  hipMemsetAsync(cnt, 0, NEXP * 4, stream);
  k_detect<<<1, 64, 0, stream>>>(idx, flag);
  k_count<<<(NK + 255) / 256, 256, 0, stream>>>(idx, flag, cnt);
  k_scan<<<1, 256, 0, stream>>>(cnt, offp, off2, texp, tok);
  k_scatter<<<(NK + 255) / 256, 256, 0, stream>>>(idx, flag, off2, tok, pos);
  k_cvt_x<<<(N_TOK * DDIM / 8 + 255) / 256, 256, 0, stream>>>(x, Xb);
  k_transpose<<<dim3(HDIM / 32, DDIM / 32, NEXP), 256, 0, stream>>>(W1, W1t, DDIM, HDIM);
  k_transpose<<<dim3(DDIM / 32, HDIM / 32, NEXP), 256, 0, stream>>>(W2, W2t, HDIM, DDIM);

  for (int base = 0; base < MAXT; base += ts) {
    int cnt_t = (MAXT - base < ts) ? (MAXT - base) : ts;
    k_gemm<0><<<dim3(HDIM / BN, cnt_t), 256, 0, stream>>>(
        Xb, W1t, b1, texp, tok, DDIM, HDIM, base, (void*)hbuf);
    k_gemm<1><<<dim3(DDIM / BN, cnt_t), 256, 0, stream>>>(
        hbuf, W2t, b2, texp, tok, HDIM, DDIM, base, (void*)ybuf);
  }
  k_combine<<<(N_TOK * DDIM / 4 + 255) / 256, 256, 0, stream>>>(ybuf, prob, pos, out);
}

// Round 2
// 588.378 us; speedup vs baseline: 1.0008x; 1.0008x over previous
//
#include <hip/hip_runtime.h>
#include <hip/hip_bf16.h>

#define N_TOK 8192
#define DDIM 1024
#define HDIM 4096
#define NEXP 8
#define TOPK 2
#define NK (N_TOK*TOPK)
#define BM 128
#define BN 128
#define BK 64
#define MAXT 136   // max padded M-tiles: 16384/128 + 8 pad tiles

typedef __hip_bfloat16 bf16;
typedef __attribute__((ext_vector_type(8))) short bf16x8;
typedef __attribute__((ext_vector_type(4))) float f32x4;

__device__ __forceinline__ void gload16(const void* g, void* lds) {
  auto l = (__attribute__((address_space(3))) unsigned int*)(unsigned int)(unsigned long long)lds;
  auto gg = (const __attribute__((address_space(1))) unsigned int*)(unsigned long long)g;
  __builtin_amdgcn_global_load_lds(gg, l, 16, 0, 0);
}

// ---- router ----
__global__ void k_detect(const int* __restrict__ idx, int* __restrict__ flag) {
  if (threadIdx.x == 0 && blockIdx.x == 0) {
    int allz = 1;
    for (int i = 1; i < 32; i += 2) allz &= (idx[i] == 0);
    *flag = allz ? 2 : 1;   // 2 => int64 little-endian, 1 => int32
  }
}

__global__ void k_count(const int* __restrict__ idx, const int* __restrict__ flag,
                        int* __restrict__ cnt) {
  int r = blockIdx.x * blockDim.x + threadIdx.x;
  if (r >= NK) return;
  int s = *flag;
  int e = idx[r * s];
  e = min(max(e, 0), NEXP - 1);
  atomicAdd(&cnt[e], 1);
}

__global__ void k_scan(const int* __restrict__ cnt, int* __restrict__ offp,
                       int* __restrict__ off2, int* __restrict__ texp,
                       int* __restrict__ tok) {
  __shared__ int so[NEXP + 1], sc[NEXP];
  int tid = threadIdx.x;
  if (tid == 0) {
    int cum = 0;
    for (int e = 0; e < NEXP; e++) {
      so[e] = cum; sc[e] = cnt[e];
      cum += ((cnt[e] + BM - 1) / BM) * BM;
    }
    so[NEXP] = cum;
    for (int e = 0; e <= NEXP; e++) offp[e] = so[e];
  }
  __syncthreads();
  if (tid < NEXP) off2[tid] = so[tid];
  int total_tiles = so[NEXP] / BM;
  for (int t = tid; t < MAXT; t += blockDim.x) {
    int e = -1;
    if (t < total_tiles) {
      for (int q = 0; q < NEXP; q++)
        if (t * BM >= so[q] && t * BM < so[q + 1]) e = q;
    }
    texp[t] = e;
  }
  for (int e = 0; e < NEXP; e++) {
    int start = so[e] + sc[e], end = so[e + 1];
    for (int i = start + tid; i < end; i += blockDim.x) tok[i] = 0;
  }
}

__global__ void k_scatter(const int* __restrict__ idx, const int* __restrict__ flag,
                          int* __restrict__ off2, int* __restrict__ tok,
                          int* __restrict__ pos) {
  int r = blockIdx.x * blockDim.x + threadIdx.x;
  if (r >= NK) return;
  int s = *flag;
  int e = idx[r * s];
  e = min(max(e, 0), NEXP - 1);
  int p = atomicAdd(&off2[e], 1);
  tok[p] = r >> 1;
  pos[r] = p;
}

// ---- converts ----
__global__ void k_cvt_x(const float* __restrict__ x, bf16* __restrict__ xb) {
  int i = blockIdx.x * blockDim.x + threadIdx.x;   // over N*D/8
  if (i >= N_TOK * DDIM / 8) return;
  float4 a = ((const float4*)x)[(size_t)i * 2];
  float4 b = ((const float4*)x)[(size_t)i * 2 + 1];
  union { bf16 h[8]; uint4 v; } u;
  u.h[0] = __float2bfloat16(a.x); u.h[1] = __float2bfloat16(a.y);
  u.h[2] = __float2bfloat16(a.z); u.h[3] = __float2bfloat16(a.w);
  u.h[4] = __float2bfloat16(b.x); u.h[5] = __float2bfloat16(b.y);
  u.h[6] = __float2bfloat16(b.z); u.h[7] = __float2bfloat16(b.w);
  *(uint4*)&xb[(size_t)i * 8] = u.v;
}

// [E][R][C] fp32 -> [E][C][R] bf16, ushort2 (4B/lane) stores
__global__ void k_transpose(const float* __restrict__ in, bf16* __restrict__ out,
                            int R, int C) {
  __shared__ float t[32][33];
  size_t ebase = (size_t)blockIdx.z * R * C;
  int tx = threadIdx.x & 31, ty = threadIdx.x >> 5;
  int c0 = blockIdx.x * 32, r0 = blockIdx.y * 32;
#pragma unroll
  for (int j = 0; j < 4; j++)
    t[ty + j * 8][tx] = in[ebase + (size_t)(r0 + ty + j * 8) * C + c0 + tx];
  __syncthreads();
  int tx2 = (threadIdx.x & 15) * 2;   // r-pair within tile
  int cy  = threadIdx.x >> 4;         // 0..15
#pragma unroll
  for (int p = 0; p < 2; p++) {
    int c = cy + p * 16;
    union { bf16 h[2]; unsigned int u; } w;
    w.h[0] = __float2bfloat16(t[tx2][c]);
    w.h[1] = __float2bfloat16(t[tx2 + 1][c]);
    *(unsigned int*)&out[ebase + (size_t)(c0 + c) * R + r0 + tx2] = w.u;
  }
}

// ---- grouped GEMM ----
// MODE 0: A gathered by tok ids (Xb), +bias ReLU, bf16 out (slice-local rows)
// MODE 1: A = h (slice-local rows), +bias, f32 out (global rows)
template<int MODE>
__global__ __launch_bounds__(256, 3) void k_gemm(
    const bf16* __restrict__ A, const bf16* __restrict__ Bt,
    const float* __restrict__ bias, const int* __restrict__ texp,
    const int* __restrict__ tok, int K, int Ncols, int tile_base,
    void* __restrict__ Cout)
{
  int tm = tile_base + blockIdx.y;
  int e = texp[tm];
  if (e < 0) return;
  int tn = blockIdx.x;
  int tid = threadIdx.x, lane = tid & 63, wid = tid >> 6;
  int wm = wid >> 1, wn = wid & 1;

  __shared__ __align__(16) bf16 As[BM * BK];
  __shared__ __align__(16) bf16 Bs[BN * BK];

  const bf16* Bexp = Bt + ((size_t)e * Ncols + (size_t)tn * BN) * K;

  // Hoist all staging source addresses out of the K-loop (incl. tok gather).
  const bf16* asrc[4];
  const bf16* bsrc[4];
#pragma unroll
  for (int it = 0; it < 4; ++it) {
    int ch = it * 256 + tid;
    int i = ch >> 3, c = ch & 7;
    int cs = c ^ (i & 7);                  // source-side swizzle (rule #21)
    int arow;
    if (MODE == 0) arow = tok[tm * BM + i];
    else           arow = (tm - tile_base) * BM + i;
    asrc[it] = A + (size_t)arow * K + cs * 8;
    bsrc[it] = Bexp + (size_t)i * K + cs * 8;
  }

  f32x4 acc[4][4];
#pragma unroll
  for (int i = 0; i < 4; i++)
#pragma unroll
    for (int j = 0; j < 4; j++) acc[i][j] = (f32x4){0.f, 0.f, 0.f, 0.f};

  for (int k0 = 0; k0 < K; k0 += BK) {
#pragma unroll
    for (int it = 0; it < 4; ++it)
      gload16(asrc[it] + k0, (char*)As + (it * 256 + wid * 64) * 16);
#pragma unroll
    for (int it = 0; it < 4; ++it)
      gload16(bsrc[it] + k0, (char*)Bs + (it * 256 + wid * 64) * 16);
    asm volatile("s_waitcnt vmcnt(0)" ::: "memory");
    __syncthreads();

#pragma unroll
    for (int kh = 0; kh < 2; ++kh) {
      bf16x8 av[4], bv[4];
      int lr = lane & 15, kg = lane >> 4;
#pragma unroll
      for (int mi = 0; mi < 4; mi++) {
        int m = wm * 64 + mi * 16 + lr;
        int ph = (kh * 4 + kg) ^ (m & 7);    // swizzled read
        av[mi] = *(const bf16x8*)&As[m * BK + ph * 8];
      }
#pragma unroll
      for (int ni = 0; ni < 4; ni++) {
        int n = wn * 64 + ni * 16 + lr;
        int ph = (kh * 4 + kg) ^ (n & 7);
        bv[ni] = *(const bf16x8*)&Bs[n * BK + ph * 8];
      }
#pragma unroll
      for (int mi = 0; mi < 4; mi++)
#pragma unroll
        for (int ni = 0; ni < 4; ni++)
          acc[mi][ni] = __builtin_amdgcn_mfma_f32_16x16x32_bf16(
              av[mi], bv[ni], acc[mi][ni], 0, 0, 0);
    }
    __syncthreads();
  }

  const float* be = bias + (size_t)e * Ncols;
  int lr = lane & 15, rg = lane >> 4;
#pragma unroll
  for (int ni = 0; ni < 4; ++ni) {
    int n = tn * BN + wn * 64 + ni * 16 + lr;
    float bv = be[n];
#pragma unroll
    for (int mi = 0; mi < 4; ++mi) {
#pragma unroll
      for (int j = 0; j < 4; j++) {
        int mrow = wm * 64 + mi * 16 + rg * 4 + j;   // row within tile (C/D map m89)
        float v = acc[mi][ni][j] + bv;
        if (MODE == 0) {
          v = fmaxf(v, 0.f);
          ((bf16*)Cout)[(size_t)((tm - tile_base) * BM + mrow) * Ncols + n] =
              __float2bfloat16(v);
        } else {
          ((float*)Cout)[(size_t)(tm * BM + mrow) * Ncols + n] = v;
        }
      }
    }
  }
}

// ---- combine ----
__global__ void k_combine(const float* __restrict__ y, const float* __restrict__ prob,
                          const int* __restrict__ pos, float* __restrict__ out) {
  int gid = blockIdx.x * blockDim.x + threadIdx.x;  // over N*D/4
  if (gid >= N_TOK * DDIM / 4) return;
  int n = gid / (DDIM / 4);
  int d4 = gid % (DDIM / 4);
  int r0 = pos[2 * n], r1 = pos[2 * n + 1];
  float p0 = prob[2 * n], p1 = prob[2 * n + 1];
  float4 a = *(const float4*)&y[(size_t)r0 * DDIM + (size_t)d4 * 4];
  float4 b = *(const float4*)&y[(size_t)r1 * DDIM + (size_t)d4 * 4];
  float4 o;
  o.x = p0 * a.x + p1 * b.x; o.y = p0 * a.y + p1 * b.y;
  o.z = p0 * a.z + p1 * b.z; o.w = p0 * a.w + p1 * b.w;
  *(float4*)&out[(size_t)n * DDIM + (size_t)d4 * 4] = o;
  if (gid == 0) out[(size_t)N_TOK * DDIM] = 0.f;   // total_loss
}

extern "C" void kernel_launch(void* const* d_in, const int* in_sizes, int n_in,
                              void* d_out, int out_size, void* d_ws, size_t ws_size,
                              hipStream_t stream) {
  const float* x    = (const float*)d_in[0];
  const float* prob = (const float*)d_in[1];
  const int*   idx  = (const int*)d_in[2];
  const float* W1   = (const float*)d_in[3];
  const float* b1   = (const float*)d_in[4];
  const float* W2   = (const float*)d_in[5];
  const float* b2   = (const float*)d_in[6];
  float* out = (float*)d_out;

  char* ws = (char*)d_ws;
  size_t cur = 0;
  auto alloc = [&](size_t bytes) -> void* {
    cur = (cur + 255) & ~(size_t)255;
    void* p = ws + cur; cur += bytes; return p;
  };
  int* cnt   = (int*)alloc(NEXP * 4);
  int* offp  = (int*)alloc((NEXP + 1) * 4);
  int* off2  = (int*)alloc(NEXP * 4);
  int* flag  = (int*)alloc(4);
  int* texp  = (int*)alloc(MAXT * 4);
  int* tok   = (int*)alloc((size_t)MAXT * BM * 4);
  int* pos   = (int*)alloc((size_t)NK * 4);
  bf16* Xb   = (bf16*)alloc((size_t)N_TOK * DDIM * 2);
  bf16* W1t  = (bf16*)alloc((size_t)NEXP * HDIM * DDIM * 2);
  bf16* W2t  = (bf16*)alloc((size_t)NEXP * DDIM * HDIM * 2);
  float* ybuf = (float*)alloc((size_t)MAXT * BM * DDIM * 4);
  cur = (cur + 255) & ~(size_t)255;
  size_t h_off = cur;
  size_t h_avail = ws_size > h_off ? ws_size - h_off : 0;
  long long ts_ll = (long long)(h_avail / ((size_t)BM * HDIM * 2));
  int ts = (int)(ts_ll < 1 ? 1 : (ts_ll > MAXT ? MAXT : ts_ll));
  bf16* hbuf = (bf16*)(ws + h_off);

  hipMemsetAsync(cnt, 0, NEXP * 4, stream);
  k_detect<<<1, 64, 0, stream>>>(idx, flag);
  k_count<<<(NK + 255) / 256, 256, 0, stream>>>(idx, flag, cnt);
  k_scan<<<1, 256, 0, stream>>>(cnt, offp, off2, texp, tok);
  k_scatter<<<(NK + 255) / 256, 256, 0, stream>>>(idx, flag, off2, tok, pos);
  k_cvt_x<<<(N_TOK * DDIM / 8 + 255) / 256, 256, 0, stream>>>(x, Xb);
  k_transpose<<<dim3(HDIM / 32, DDIM / 32, NEXP), 256, 0, stream>>>(W1, W1t, DDIM, HDIM);
  k_transpose<<<dim3(DDIM / 32, HDIM / 32, NEXP), 256, 0, stream>>>(W2, W2t, HDIM, DDIM);

  for (int base = 0; base < MAXT; base += ts) {
    int cnt_t = (MAXT - base < ts) ? (MAXT - base) : ts;
    k_gemm<0><<<dim3(HDIM / BN, cnt_t), 256, 0, stream>>>(
        Xb, W1t, b1, texp, tok, DDIM, HDIM, base, (void*)hbuf);
    k_gemm<1><<<dim3(DDIM / BN, cnt_t), 256, 0, stream>>>(
        hbuf, W2t, b2, texp, tok, HDIM, DDIM, base, (void*)ybuf);
  }
  k_combine<<<(N_TOK * DDIM / 4 + 255) / 256, 256, 0, stream>>>(ybuf, prob, pos, out);
}